// Round 12
// baseline (22.738 us; speedup 1.0000x reference)
//
#include <hip/hip_runtime.h>

// SegmentationLoss: scalar = sum_{b,l,i} g[b,l,i] * sqrt(sum_f (p[b,l,f]-g[b,l,i])^2)
// input (8,16,256,256) f32, target (8,8,256,256) f32, out: 1 f32.
// Identity: sum_f (p_f - g)^2 = s2 - 2 g s1 + NF g^2,  s1=sum_f p_f, s2=sum_f p_f^2.
//
// Round-12: DIAGNOSTIC, not an optimization. Exact R10 kernels, but stage1 is
// dispatched TWICE (idempotent: same partials written twice; NT loads leave
// caches cold so both runs are steady-state). dur(R12) - dur(R10) = isolated
// stage1 duration:
//   ~8.5us  -> stage1 at HBM floor -> declare roofline, revert to R10.
//   ~11us   -> stage1 at ~4.6 TB/s -> ~3us read-path headroom to chase.
//
// Locked-in: NT loads -1.9us (R10); occupancy null under NT (R11=R10);
// in-kernel coherent finishes lose to 2nd dispatch (R4, R6); same-line
// atomics ~30ns serialized (R1/R2); stage1 sync structure irrelevant (R3=R5=R7).
// History: R1 24.4 | R2 41.8 | R3 15.7 | R4 32.4 | R5 16.3 | R6 21.7
//        | R7 16.6 | R8 16.3 | R9 cfail | R10 14.65 | R11 14.59.

#define HW    (256 * 256)
#define NF    16
#define NI    8
#define BSZ   8
#define NBLK  512

typedef float f32x4 __attribute__((ext_vector_type(4)));

__global__ __launch_bounds__(256) void seg_loss_stage1(const float* __restrict__ input,
                                                       const float* __restrict__ target,
                                                       float* __restrict__ partial) {
    const int tid  = blockIdx.x * blockDim.x + threadIdx.x;   // 0 .. 131071
    const int loc0 = tid << 2;                                // 4 consecutive locations
    const int b    = loc0 >> 16;
    const int l    = loc0 & (HW - 1);

    const f32x4* ip = reinterpret_cast<const f32x4*>(input  + (size_t)b * NF * HW + l);
    const f32x4* tp = reinterpret_cast<const f32x4*>(target + (size_t)b * NI * HW + l);

    f32x4 s1 = (f32x4)(0.f);
    f32x4 s2 = (f32x4)(0.f);
#pragma unroll
    for (int f = 0; f < NF; ++f) {
        f32x4 p = __builtin_nontemporal_load(&ip[f * (HW / 4)]);
        s1 += p;
        s2 += p * p;
    }

    float acc = 0.f;
#pragma unroll
    for (int i = 0; i < NI; ++i) {
        f32x4 g = __builtin_nontemporal_load(&tp[i * (HW / 4)]);
        f32x4 q = s2 - 2.f * g * s1 + (float)NF * g * g;
        acc += g.x * sqrtf(fmaxf(q.x, 0.f));
        acc += g.y * sqrtf(fmaxf(q.y, 0.f));
        acc += g.z * sqrtf(fmaxf(q.z, 0.f));
        acc += g.w * sqrtf(fmaxf(q.w, 0.f));
    }

    // Wave reduction; lane 0 writes this wave's partial. No LDS/barriers/atomics.
#pragma unroll
    for (int off = 32; off > 0; off >>= 1)
        acc += __shfl_down(acc, off, 64);

    const int lane = threadIdx.x & 63;
    const int gwid = (blockIdx.x << 2) | (threadIdx.x >> 6);   // 0 .. 2047
    if (lane == 0) partial[gwid] = acc;
}

__global__ __launch_bounds__(64) void seg_loss_stage2(const float* __restrict__ partial,
                                                      float* __restrict__ out) {
    const f32x4* p4 = reinterpret_cast<const f32x4*>(partial);  // 512 f32x4
    float s = 0.f;
#pragma unroll
    for (int k = 0; k < 8; ++k) {                 // lane i reads p4[i + 64k]
        f32x4 v = p4[threadIdx.x + (k << 6)];
        s += v.x + v.y + v.z + v.w;
    }
#pragma unroll
    for (int off = 32; off > 0; off >>= 1)
        s += __shfl_down(s, off, 64);
    if (threadIdx.x == 0) out[0] = s;
}

extern "C" void kernel_launch(void* const* d_in, const int* in_sizes, int n_in,
                              void* d_out, int out_size, void* d_ws, size_t ws_size,
                              hipStream_t stream) {
    const float* input  = (const float*)d_in[0];
    const float* target = (const float*)d_in[1];
    float* out     = (float*)d_out;
    float* partial = (float*)d_ws;   // 2048 floats = 8 KB scratch

    // Diagnostic double-dispatch of stage1 (idempotent, deterministic).
    seg_loss_stage1<<<NBLK, 256, 0, stream>>>(input, target, partial);
    seg_loss_stage1<<<NBLK, 256, 0, stream>>>(input, target, partial);
    seg_loss_stage2<<<1, 64, 0, stream>>>(partial, out);
}

// Round 13
// 14.379 us; speedup vs baseline: 1.5813x; 1.5813x over previous
//
#include <hip/hip_runtime.h>

// SegmentationLoss: scalar = sum_{b,l,i} g[b,l,i] * sqrt(sum_f (p[b,l,f]-g[b,l,i])^2)
// input (8,16,256,256) f32, target (8,8,256,256) f32, out: 1 f32.
// Identity: sum_f (p_f - g)^2 = s2 - 2 g s1 + NF g^2,  s1=sum_f p_f, s2=sum_f p_f^2.
//
// FINAL (= R10): two kernels, zero-sync stage1 with nontemporal loads.
//   stage1: 512 blk x 256 thr; thread owns one float4 group; 24 independent
//           16B NT loads (stream-once data, no cache allocation); wave shfl
//           reduce; lane 0 writes partial[waveId]. No LDS/barriers/atomics.
//   stage2: one 64-lane wave sums the 2048 partials -> out[0].
//
// Measured decomposition (R12 double-dispatch diagnostic): stage1 isolated
// = 8.09us = 6.22 TB/s read BW ~= achievable HBM ceiling (6.3). Residual
// ~6.5us = stage2 + 2x graph dispatch + drain edge; every in-kernel finish
// alternative measured worse (R4 threadfence 32.4, R6 atomic-tree 21.7).
// Lessons: NT loads -1.9us; same-line atomics ~30ns each serialized;
// sync structure / granularity / occupancy all null (R3=R5=R7=R8, R10=R11).
// History: R1 24.4 | R2 41.8 | R3 15.7 | R4 32.4 | R5 16.3 | R6 21.7
//        | R7 16.6 | R8 16.3 | R9 cfail | R10 14.65 | R11 14.59 | R12 diag 22.7.

#define HW    (256 * 256)
#define NF    16
#define NI    8
#define BSZ   8
#define NBLK  512

typedef float f32x4 __attribute__((ext_vector_type(4)));

__global__ __launch_bounds__(256) void seg_loss_stage1(const float* __restrict__ input,
                                                       const float* __restrict__ target,
                                                       float* __restrict__ partial) {
    const int tid  = blockIdx.x * blockDim.x + threadIdx.x;   // 0 .. 131071
    const int loc0 = tid << 2;                                // 4 consecutive locations
    const int b    = loc0 >> 16;
    const int l    = loc0 & (HW - 1);

    const f32x4* ip = reinterpret_cast<const f32x4*>(input  + (size_t)b * NF * HW + l);
    const f32x4* tp = reinterpret_cast<const f32x4*>(target + (size_t)b * NI * HW + l);

    f32x4 s1 = (f32x4)(0.f);
    f32x4 s2 = (f32x4)(0.f);
#pragma unroll
    for (int f = 0; f < NF; ++f) {
        f32x4 p = __builtin_nontemporal_load(&ip[f * (HW / 4)]);
        s1 += p;
        s2 += p * p;
    }

    float acc = 0.f;
#pragma unroll
    for (int i = 0; i < NI; ++i) {
        f32x4 g = __builtin_nontemporal_load(&tp[i * (HW / 4)]);
        f32x4 q = s2 - 2.f * g * s1 + (float)NF * g * g;
        acc += g.x * sqrtf(fmaxf(q.x, 0.f));
        acc += g.y * sqrtf(fmaxf(q.y, 0.f));
        acc += g.z * sqrtf(fmaxf(q.z, 0.f));
        acc += g.w * sqrtf(fmaxf(q.w, 0.f));
    }

    // Wave reduction; lane 0 writes this wave's partial. No LDS/barriers/atomics.
#pragma unroll
    for (int off = 32; off > 0; off >>= 1)
        acc += __shfl_down(acc, off, 64);

    const int lane = threadIdx.x & 63;
    const int gwid = (blockIdx.x << 2) | (threadIdx.x >> 6);   // 0 .. 2047
    if (lane == 0) partial[gwid] = acc;
}

__global__ __launch_bounds__(64) void seg_loss_stage2(const float* __restrict__ partial,
                                                      float* __restrict__ out) {
    const f32x4* p4 = reinterpret_cast<const f32x4*>(partial);  // 512 f32x4
    float s = 0.f;
#pragma unroll
    for (int k = 0; k < 8; ++k) {                 // lane i reads p4[i + 64k]
        f32x4 v = p4[threadIdx.x + (k << 6)];
        s += v.x + v.y + v.z + v.w;
    }
#pragma unroll
    for (int off = 32; off > 0; off >>= 1)
        s += __shfl_down(s, off, 64);
    if (threadIdx.x == 0) out[0] = s;
}

extern "C" void kernel_launch(void* const* d_in, const int* in_sizes, int n_in,
                              void* d_out, int out_size, void* d_ws, size_t ws_size,
                              hipStream_t stream) {
    const float* input  = (const float*)d_in[0];
    const float* target = (const float*)d_in[1];
    float* out     = (float*)d_out;
    float* partial = (float*)d_ws;   // 2048 floats = 8 KB scratch

    seg_loss_stage1<<<NBLK, 256, 0, stream>>>(input, target, partial);
    seg_loss_stage2<<<1, 64, 0, stream>>>(partial, out);
}